// Round 1
// baseline (8904.375 us; speedup 1.0000x reference)
//
#include <hip/hip_runtime.h>

#define BATCH 64
#define SEQ   512
#define INP   512
#define HID   1024
#define MAGIC 0x13570000u

// ============================================================================
// Phase 1: out[m][n] = sum_f X[m][f] * Wih[n][f] + bih[n] + bhh[n]
//   m = b*SEQ + s  (32768), n = 0..1023, f = 0..511
// Classic fp32 SGEMM: 128x128 tile, BK=8, 256 threads, 8x8 micro (split +0/+64)
// ============================================================================
__global__ __launch_bounds__(256) void xw_gemm(
    const float* __restrict__ X, const float* __restrict__ Wih,
    const float* __restrict__ bih, const float* __restrict__ bhh,
    float* __restrict__ out)
{
    __shared__ float As[8][128];
    __shared__ float Bs[8][128];
    const int t  = threadIdx.x;
    const int m0 = blockIdx.x * 128;
    const int n0 = blockIdx.y * 128;
    const int lr = t >> 1;           // 0..127 tile row for staging
    const int lk = (t & 1) * 4;      // 0 | 4
    const int ty = t >> 4;           // 0..15 (m micro position)
    const int tx = t & 15;           // 0..15 (n micro position)

    float acc[8][8];
#pragma unroll
    for (int i = 0; i < 8; ++i)
#pragma unroll
        for (int j = 0; j < 8; ++j) acc[i][j] = 0.f;

    const float* xrow = X   + (size_t)(m0 + lr) * INP + lk;
    const float* wrow = Wih + (size_t)(n0 + lr) * INP + lk;

    for (int k0 = 0; k0 < INP; k0 += 8) {
        float4 av = *(const float4*)(xrow + k0);
        float4 bv = *(const float4*)(wrow + k0);
        __syncthreads();   // previous tile's compute done before overwrite
        As[lk + 0][lr] = av.x; As[lk + 1][lr] = av.y;
        As[lk + 2][lr] = av.z; As[lk + 3][lr] = av.w;
        Bs[lk + 0][lr] = bv.x; Bs[lk + 1][lr] = bv.y;
        Bs[lk + 2][lr] = bv.z; Bs[lk + 3][lr] = bv.w;
        __syncthreads();
#pragma unroll
        for (int kk = 0; kk < 8; ++kk) {
            float4 a0 = *(const float4*)&As[kk][ty * 4];
            float4 a1 = *(const float4*)&As[kk][64 + ty * 4];
            float4 b0 = *(const float4*)&Bs[kk][tx * 4];
            float4 b1 = *(const float4*)&Bs[kk][64 + tx * 4];
            float am[8] = {a0.x, a0.y, a0.z, a0.w, a1.x, a1.y, a1.z, a1.w};
            float bn[8] = {b0.x, b0.y, b0.z, b0.w, b1.x, b1.y, b1.z, b1.w};
#pragma unroll
            for (int i = 0; i < 8; ++i)
#pragma unroll
                for (int j = 0; j < 8; ++j)
                    acc[i][j] = fmaf(am[i], bn[j], acc[i][j]);
        }
    }

    // epilogue: add (b_ih + b_hh), store
    const int nA = n0 + tx * 4;
    const int nB = n0 + 64 + tx * 4;
    float4 bA1 = *(const float4*)(bih + nA);
    float4 bA2 = *(const float4*)(bhh + nA);
    float4 bB1 = *(const float4*)(bih + nB);
    float4 bB2 = *(const float4*)(bhh + nB);
    float4 biasA = make_float4(bA1.x + bA2.x, bA1.y + bA2.y, bA1.z + bA2.z, bA1.w + bA2.w);
    float4 biasB = make_float4(bB1.x + bB2.x, bB1.y + bB2.y, bB1.z + bB2.z, bB1.w + bB2.w);

#pragma unroll
    for (int i = 0; i < 8; ++i) {
        int mloc = (i < 4) ? (ty * 4 + i) : (64 + ty * 4 + (i - 4));
        size_t m = (size_t)(m0 + mloc);
        float4 vA = make_float4(acc[i][0] + biasA.x, acc[i][1] + biasA.y,
                                acc[i][2] + biasA.z, acc[i][3] + biasA.w);
        float4 vB = make_float4(acc[i][4] + biasB.x, acc[i][5] + biasB.y,
                                acc[i][6] + biasB.z, acc[i][7] + biasB.w);
        *(float4*)(out + m * HID + nA) = vA;
        *(float4*)(out + m * HID + nB) = vB;
    }
}

// ============================================================================
// Phase 2: persistent sequential scan, in-place on out (out holds xw, becomes h)
//   h[b][j] at step s: out[b][s][j] = tanh(xw + sum_k out[b][s-1][k]*Whh[j][k])
// 256 blocks = 4 batch-groups (16 batches) x 64 j-tiles (16 j).
// Per-group barrier via magic flags in d_ws (0xAA poison != magic, slots mod 8).
// W tile staged once in 64KB LDS with diagonal skew for conflict-free b128.
// Wave = batch quad; lane = (kchunk<<4)|j ; kc partials reduced by shfl_xor.
// ============================================================================
__global__ __launch_bounds__(256) void rnn_scan(
    const float* __restrict__ Whh, float* __restrict__ out,
    unsigned* __restrict__ flags)
{
    __shared__ float4 Wlds[16][256];   // 64 KB; row r, logical col c stored at (c+r)&255

    const int t  = threadIdx.x;
    const int g  = blockIdx.x >> 6;    // batch group 0..3
    const int jt = blockIdx.x & 63;    // j tile 0..63

    // ---- stage W tile rows jt*16 .. jt*16+15 (once) ----
    {
        const int r  = t >> 4;         // 0..15
        const int cb = t & 15;
        const float4* src = (const float4*)(Whh + (size_t)(jt * 16 + r) * HID);
#pragma unroll
        for (int i = 0; i < 16; ++i) {
            int c4 = i * 16 + cb;                  // logical float4 col 0..255
            Wlds[r][(c4 + r) & 255] = src[c4];     // diagonal skew
        }
    }

    const int lane = t & 63;
    const int wv   = t >> 6;           // wave id = batch quad 0..3
    const int kc   = lane >> 4;        // k chunk 0..3 (quarter-wave uniform)
    const int jl   = lane & 15;        // j within tile
    const int bb   = g * 16 + wv * 4;  // this wave's 4 batches

    __syncthreads();

    for (int s = 0; s < SEQ; ++s) {
        float a0 = 0.f, a1 = 0.f, a2 = 0.f, a3 = 0.f;

        if (s > 0) {
            // ---- group barrier: all 64 j-tiles of group g finished step s-1 ----
            if (t < 64) {
                const unsigned want = MAGIC + (unsigned)(s - 1);
                unsigned* f = flags + ((((s - 1) & 7) * 4 + g) * 64 + t);
                while (__hip_atomic_load(f, __ATOMIC_RELAXED, __HIP_MEMORY_SCOPE_AGENT) != want)
                    __builtin_amdgcn_s_sleep(1);
            }
            __syncthreads();
            __builtin_amdgcn_fence(__ATOMIC_ACQUIRE, "agent");  // invalidate stale cache

            const float4* h0 = (const float4*)(out + ((size_t)(bb + 0) * SEQ + (s - 1)) * HID);
            const float4* h1 = (const float4*)(out + ((size_t)(bb + 1) * SEQ + (s - 1)) * HID);
            const float4* h2 = (const float4*)(out + ((size_t)(bb + 2) * SEQ + (s - 1)) * HID);
            const float4* h3 = (const float4*)(out + ((size_t)(bb + 3) * SEQ + (s - 1)) * HID);

#pragma unroll 4
            for (int i = 0; i < 64; ++i) {
                const int L = kc * 64 + i;                       // logical f4 col
                const float4 w4 = Wlds[jl][(L + jl) & 255];      // skew-corrected
                const float4 x0 = h0[L];
                const float4 x1 = h1[L];
                const float4 x2 = h2[L];
                const float4 x3 = h3[L];
                a0 = fmaf(x0.x, w4.x, a0); a0 = fmaf(x0.y, w4.y, a0);
                a0 = fmaf(x0.z, w4.z, a0); a0 = fmaf(x0.w, w4.w, a0);
                a1 = fmaf(x1.x, w4.x, a1); a1 = fmaf(x1.y, w4.y, a1);
                a1 = fmaf(x1.z, w4.z, a1); a1 = fmaf(x1.w, w4.w, a1);
                a2 = fmaf(x2.x, w4.x, a2); a2 = fmaf(x2.y, w4.y, a2);
                a2 = fmaf(x2.z, w4.z, a2); a2 = fmaf(x2.w, w4.w, a2);
                a3 = fmaf(x3.x, w4.x, a3); a3 = fmaf(x3.y, w4.y, a3);
                a3 = fmaf(x3.z, w4.z, a3); a3 = fmaf(x3.w, w4.w, a3);
            }
            // ---- reduce k-chunk partials across lanes (kc in lane>>4) ----
            a0 += __shfl_xor(a0, 16); a0 += __shfl_xor(a0, 32);
            a1 += __shfl_xor(a1, 16); a1 += __shfl_xor(a1, 32);
            a2 += __shfl_xor(a2, 16); a2 += __shfl_xor(a2, 32);
            a3 += __shfl_xor(a3, 16); a3 += __shfl_xor(a3, 32);
        }

        // ---- finalize: lanes 0..15 of each wave write 4 outputs ----
        if (lane < 16) {
            const int j = jt * 16 + jl;
            float* p0 = out + ((size_t)(bb + 0) * SEQ + s) * HID + j;
            float* p1 = out + ((size_t)(bb + 1) * SEQ + s) * HID + j;
            float* p2 = out + ((size_t)(bb + 2) * SEQ + s) * HID + j;
            float* p3 = out + ((size_t)(bb + 3) * SEQ + s) * HID + j;
            float v0 = tanhf(*p0 + a0);
            float v1 = tanhf(*p1 + a1);
            float v2 = tanhf(*p2 + a2);
            float v3 = tanhf(*p3 + a3);
            // agent-scope stores: visible across XCDs once vmcnt-drained
            __hip_atomic_store(p0, v0, __ATOMIC_RELAXED, __HIP_MEMORY_SCOPE_AGENT);
            __hip_atomic_store(p1, v1, __ATOMIC_RELAXED, __HIP_MEMORY_SCOPE_AGENT);
            __hip_atomic_store(p2, v2, __ATOMIC_RELAXED, __HIP_MEMORY_SCOPE_AGENT);
            __hip_atomic_store(p3, v3, __ATOMIC_RELAXED, __HIP_MEMORY_SCOPE_AGENT);
        }
        __syncthreads();   // drains vmcnt(0): all block stores globally visible
        if (t == 0)
            __hip_atomic_store(flags + (((s & 7) * 4 + g) * 64 + jt),
                               MAGIC + (unsigned)s,
                               __ATOMIC_RELAXED, __HIP_MEMORY_SCOPE_AGENT);
    }
}

// ============================================================================
extern "C" void kernel_launch(void* const* d_in, const int* in_sizes, int n_in,
                              void* d_out, int out_size, void* d_ws, size_t ws_size,
                              hipStream_t stream)
{
    (void)in_sizes; (void)n_in; (void)out_size; (void)ws_size;
    const float* x   = (const float*)d_in[0];   // (64,512,512)
    const float* Wih = (const float*)d_in[1];   // (1024,512)
    const float* Whh = (const float*)d_in[2];   // (1024,1024)
    const float* bih = (const float*)d_in[3];   // (1024,)
    const float* bhh = (const float*)d_in[4];   // (1024,)
    float* out = (float*)d_out;                 // (64,512,1024)
    unsigned* flags = (unsigned*)d_ws;          // 8 KB of flag slots (poison-safe)

    dim3 g1(BATCH * SEQ / 128, HID / 128);      // (256, 8)
    xw_gemm<<<g1, 256, 0, stream>>>(x, Wih, bih, bhh, out);
    rnn_scan<<<256, 256, 0, stream>>>(Whh, out, flags);
}